// Round 18
// baseline (382.586 us; speedup 1.0000x reference)
//
#include <hip/hip_runtime.h>
#include <math.h>

#define D 128
#define BCAP 5120   // padded pair-slots per bucket (mean 4096, sigma 64 -> +16 sigma)

typedef short s8v __attribute__((ext_vector_type(8)));
typedef float f32x4 __attribute__((ext_vector_type(4)));
typedef unsigned short u16x8 __attribute__((ext_vector_type(8)));

__device__ __forceinline__ unsigned short f2bf(float f) {
  union { float f; unsigned u; } c; c.f = f;
  unsigned u = c.u;
  unsigned r = (u + 0x7fffu + ((u >> 16) & 1u)) >> 16;
  return (unsigned short)r;
}

__device__ __forceinline__ void gload_lds16(const void* g, void* l) {
  __builtin_amdgcn_global_load_lds((const __attribute__((address_space(1))) void*)g,
                                   (__attribute__((address_space(3))) void*)l, 16, 0, 0);
}

// LDS fragment address: logical (row r, chunk c) stored at chunk (r*16 + (c ^ (r&7)))
__device__ __forceinline__ int swz_chunk(int r, int c) { return (r << 4) + (c ^ (r & 7)); }

// ---------------- dispatch A': partA || weight-cvt || proj layer-0 (3-way merge) -----
__global__ __launch_bounds__(512, 4) void k_build_proj(const int* __restrict__ src,
                                                       const int* __restrict__ dst,
                                                       int* __restrict__ cursor,
                                                       unsigned* __restrict__ pairs, int E_,
                                                       const float* __restrict__ Wp,
                                                       const float* __restrict__ Wl,
                                                       const float* __restrict__ Wr,
                                                       const float* __restrict__ Wlo,
                                                       const float* __restrict__ Wro,
                                                       unsigned short* __restrict__ Wb,
                                                       const float* __restrict__ Av,
                                                       const float* __restrict__ bias,
                                                       unsigned short* __restrict__ hout,
                                                       unsigned short* __restrict__ xb_out,
                                                       int n, int nA, int nC) {
  __shared__ __align__(16) unsigned short Wlds[128 * 128];
  __shared__ int hist[512];
  __shared__ int gbase[512];
  __shared__ int lim[512];
  int t = threadIdx.x;
  int bid = blockIdx.x;

  if (bid < nA) {
    // ---------------- partA ----------------
    int base = bid * 8192;
    hist[t] = 0;
    __syncthreads();
    unsigned p_[16];
    int k_[16];
#pragma unroll
    for (int i = 0; i < 16; i++) {
      int e = base + i * 512 + t;
      if (e < E_) {
        int s = src[e], d = dst[e];
        p_[i] = ((unsigned)s << 8) | (unsigned)(d & 255);
        k_[i] = d >> 8;
        atomicAdd(&hist[k_[i]], 1);
      } else {
        k_[i] = -1;
      }
    }
    __syncthreads();
    {
      int c = hist[t];
      int start = c ? atomicAdd(&cursor[t], c) : 0;
      gbase[t] = t * BCAP + start;
      lim[t] = BCAP - start;   // remaining capacity in this bucket
      hist[t] = 0;
    }
    __syncthreads();
#pragma unroll
    for (int i = 0; i < 16; i++) {
      if (k_[i] >= 0) {
        int r = atomicAdd(&hist[k_[i]], 1);
        if (r < lim[k_[i]]) pairs[gbase[k_[i]] + r] = p_[i];
      }
    }
  } else if (bid < nA + nC) {
    // ---------------- weight cvt: float4 units [4096, 32768) (skip Wp layer0) ------
    int i = 4096 + (bid - nA) * 512 + t;
    const float* s;
    int off;
    if (i < 8192)       { s = Wp;  off = 0; }
    else if (i < 16384) { s = Wl;  off = 8192; }
    else if (i < 24576) { s = Wr;  off = 16384; }
    else if (i < 28672) { s = Wlo; off = 24576; }
    else                { s = Wro; off = 28672; }
    float4 a = ((const float4*)s)[i - off];
    ushort4 o;
    o.x = f2bf(a.x); o.y = f2bf(a.y); o.z = f2bf(a.z); o.w = f2bf(a.w);
    ((ushort4*)Wb)[i] = o;
  } else {
    // ---------------- proj layer 0 (self-staged fp32 Wp) ----------------
    int pbid = bid - nA - nC;
    int wv = t >> 6, l = t & 63, lg = l >> 4, ln = l & 15;
    int rb = pbid * 128 + wv * 16;
    int arow = rb + ln;
    if (arow >= n) arow = n - 1;

    // stage Wp layer-0: fp32 -> bf16, swizzled chunks, register path
#pragma unroll
    for (int i = 0; i < 4; ++i) {
      int idx = t + i * 512;        // chunk 0..2047
      int r = idx >> 4, k = idx & 15;
      int c = k ^ (r & 7);
      const float* wsrc = Wp + r * 128 + c * 8;
      float4 f0 = *(const float4*)wsrc;
      float4 f1 = *(const float4*)(wsrc + 4);
      u16x8 wb;
      wb[0] = f2bf(f0.x); wb[1] = f2bf(f0.y); wb[2] = f2bf(f0.z); wb[3] = f2bf(f0.w);
      wb[4] = f2bf(f1.x); wb[5] = f2bf(f1.y); wb[6] = f2bf(f1.z); wb[7] = f2bf(f1.w);
      *(u16x8*)&Wlds[idx * 8] = wb;
    }

    s8v a[4];
    const float* Af = Av + (size_t)arow * D + lg * 8;
#pragma unroll
    for (int ks = 0; ks < 4; ++ks) {
      float4 f0 = *(const float4*)(Af + ks * 32);
      float4 f1 = *(const float4*)(Af + ks * 32 + 4);
      s8v av;
      av[0] = (short)f2bf(f0.x); av[1] = (short)f2bf(f0.y);
      av[2] = (short)f2bf(f0.z); av[3] = (short)f2bf(f0.w);
      av[4] = (short)f2bf(f1.x); av[5] = (short)f2bf(f1.y);
      av[6] = (short)f2bf(f1.z); av[7] = (short)f2bf(f1.w);
      a[ks] = av;
      *(s8v*)(xb_out + (size_t)arow * D + lg * 8 + ks * 32) = av;
    }
    __syncthreads();

    f32x4 acc[8];
#pragma unroll
    for (int f = 0; f < 8; ++f) acc[f] = (f32x4){0.f, 0.f, 0.f, 0.f};
#pragma unroll
    for (int ks = 0; ks < 4; ++ks) {
#pragma unroll
      for (int f = 0; f < 8; ++f) {
        s8v b = *(const s8v*)&Wlds[swz_chunk(f * 16 + ln, ks * 4 + lg) * 8];
        acc[f] = __builtin_amdgcn_mfma_f32_16x16x32_bf16(a[ks], b, acc[f], 0, 0, 0);
      }
    }

#pragma unroll
    for (int r = 0; r < 4; ++r) {
      int gr = rb + 4 * lg + r;
      if (gr < n) {
#pragma unroll
        for (int f = 0; f < 8; ++f) {
          int c = f * 16 + ln;
          float v = acc[f][r] + bias[c];
          v = fmaxf(v, 0.f);
          hout[(size_t)gr * D + c] = f2bf(v);
        }
      }
    }
  }
}

// ---------------- partB (standalone): one bucket/block, 1024 thr ----------------
__global__ __launch_bounds__(1024) void k_partB(const unsigned* __restrict__ pairs,
                                                const int* __restrict__ bcnt,
                                                int* __restrict__ csrCursor,
                                                int* __restrict__ row_start,
                                                int* __restrict__ deg,
                                                int* __restrict__ csr, int n) {
  __shared__ int cnt[256];
  __shared__ int scn[256];
  __shared__ int baseSh;
  int k = blockIdx.x, t = threadIdx.x;
  int node0 = k << 8;
  int len = bcnt[k];
  if (len > BCAP) len = BCAP;
  const unsigned* pb = pairs + (size_t)k * BCAP;
  if (t == 0) baseSh = atomicAdd(csrCursor, len);
  if (t < 256) cnt[t] = 0;
  __syncthreads();
  for (int p = t; p < len; p += 1024) atomicAdd(&cnt[pb[p] & 255], 1);
  __syncthreads();
  int c = 0;
  if (t < 256) { c = cnt[t]; scn[t] = c; }
  __syncthreads();
  for (int off = 1; off < 256; off <<= 1) {
    int xv = 0;
    if (t < 256 && t >= off) xv = scn[t - off];
    __syncthreads();
    if (t < 256) scn[t] += xv;
    __syncthreads();
  }
  if (t < 256) {
    int ex = scn[t] - c;
    int node = node0 + t;
    if (node < n) { row_start[node] = baseSh + ex; deg[node] = c; }
    cnt[t] = baseSh + ex;   // running cursor per node
  }
  __syncthreads();
  for (int p = t; p < len; p += 1024) {
    unsigned pr = pb[p];
    int slot = atomicAdd(&cnt[pr & 255], 1);
    csr[slot] = (int)(pr >> 8);
  }
}

// ---------------- mean aggregation: one node per 16-lane group ----------------
__global__ __launch_bounds__(256) void k_aggregate(const unsigned short* __restrict__ h,
                                                   unsigned short* __restrict__ agg,
                                                   const int* __restrict__ row_start,
                                                   const int* __restrict__ deg,
                                                   const int* __restrict__ csr, int n) {
  int node = (blockIdx.x * 256 + threadIdx.x) >> 4;
  int li = threadIdx.x & 15;
  if (node >= n) return;
  int rs0 = row_start[node];
  int dc = deg[node];
  const int* ce = csr + rs0;
  const char* base = (const char*)h + li * 16;   // row r chunk at base + r*256

  float accL[4], accH[4];
#pragma unroll
  for (int q = 0; q < 4; q++) { accL[q] = 0.f; accH[q] = 0.f; }

#define ACCR(v)                                                        \
  {                                                                    \
    unsigned dw[4] = {(v).x, (v).y, (v).z, (v).w};                     \
    _Pragma("unroll") for (int q = 0; q < 4; q++) {                    \
      accL[q] += __uint_as_float(dw[q] << 16);                         \
      accH[q] += __uint_as_float(dw[q] & 0xffff0000u);                 \
    }                                                                  \
  }

  int e = 0;
  bool more = (3 < dc);
  int s0 = 0, s1 = 0, s2 = 0, s3 = 0;
  if (more) { s0 = ce[0]; s1 = ce[1]; s2 = ce[2]; s3 = ce[3]; }
  while (more) {
    uint4 v0 = *(const uint4*)(base + (size_t)s0 * 256);
    uint4 v1 = *(const uint4*)(base + (size_t)s1 * 256);
    uint4 v2 = *(const uint4*)(base + (size_t)s2 * 256);
    uint4 v3 = *(const uint4*)(base + (size_t)s3 * 256);
    e += 4;
    more = (e + 3 < dc);
    if (more) { s0 = ce[e]; s1 = ce[e + 1]; s2 = ce[e + 2]; s3 = ce[e + 3]; }
    ACCR(v0); ACCR(v1); ACCR(v2); ACCR(v3);
  }
  if (e < dc)     { uint4 v = *(const uint4*)(base + (size_t)ce[e] * 256);     ACCR(v); }
  if (e + 1 < dc) { uint4 v = *(const uint4*)(base + (size_t)ce[e + 1] * 256); ACCR(v); }
  if (e + 2 < dc) { uint4 v = *(const uint4*)(base + (size_t)ce[e + 2] * 256); ACCR(v); }
#undef ACCR

  float iv = 1.0f / (float)(dc > 0 ? dc : 1);
  u16x8 o;
#pragma unroll
  for (int q = 0; q < 4; q++) {
    o[2 * q] = f2bf(accL[q] * iv);
    o[2 * q + 1] = f2bf(accH[q] * iv);
  }
  *(u16x8*)(agg + (size_t)node * D + li * 8) = o;
}

// ---------------- dual GEMM: A1@W1^T + b + A2@W2^T ----------------
// W1 staged in LDS (32 KB); W2 streamed from global (32 KB, L1-resident per CU
// after first touch) -> 3 blocks/CU instead of 2 for better A-load latency cover.
// MODE 0: L2-normalize rows then relu, store bf16. MODE 1: store fp32.
template <int MODE>
__global__ __launch_bounds__(512, 6) void k_gemm_dual(const unsigned short* __restrict__ A1,
                                                      const unsigned short* __restrict__ W1,
                                                      const float* __restrict__ bias,
                                                      const unsigned short* __restrict__ A2,
                                                      const unsigned short* __restrict__ W2,
                                                      void* __restrict__ outv, int n) {
  __shared__ __align__(16) unsigned short Wlds[128 * 128];
  int t = threadIdx.x;
  int wv = t >> 6, l = t & 63, lg = l >> 4, ln = l & 15;
  int rb = blockIdx.x * 128 + wv * 16;
  int arow = rb + ln;
  if (arow >= n) arow = n - 1;
  const s8v* A1p = (const s8v*)(A1 + (size_t)arow * D + lg * 8);
  const s8v* A2p = (const s8v*)(A2 + (size_t)arow * D + lg * 8);
  s8v a1[4], a2[4];
#pragma unroll
  for (int ks = 0; ks < 4; ++ks) { a1[ks] = A1p[ks * 4]; a2[ks] = A2p[ks * 4]; }

#pragma unroll
  for (int i = 0; i < 4; ++i) {
    int idx = t + i * 512;          // chunk 0..2047
    int r = idx >> 4, k = idx & 15;
    int c = k ^ (r & 7);
    gload_lds16(W1 + r * 128 + c * 8, &Wlds[idx * 8]);
  }
  __syncthreads();

  f32x4 acc[8];
#pragma unroll
  for (int f = 0; f < 8; ++f) acc[f] = (f32x4){0.f, 0.f, 0.f, 0.f};

#pragma unroll
  for (int ks = 0; ks < 4; ++ks) {
#pragma unroll
    for (int f = 0; f < 8; ++f) {
      s8v b1 = *(const s8v*)&Wlds[swz_chunk(f * 16 + ln, ks * 4 + lg) * 8];
      const s8v* B2p = (const s8v*)(W2 + (size_t)(f * 16 + ln) * D + lg * 8);
      s8v b2 = B2p[ks * 4];
      acc[f] = __builtin_amdgcn_mfma_f32_16x16x32_bf16(a1[ks], b1, acc[f], 0, 0, 0);
      acc[f] = __builtin_amdgcn_mfma_f32_16x16x32_bf16(a2[ks], b2, acc[f], 0, 0, 0);
    }
  }

#pragma unroll
  for (int r = 0; r < 4; ++r) {
    int gr = rb + 4 * lg + r;
    float v[8];
#pragma unroll
    for (int f = 0; f < 8; ++f) v[f] = acc[f][r] + bias[f * 16 + ln];
    if (MODE == 0) {
      float ss = 0.f;
#pragma unroll
      for (int f = 0; f < 8; ++f) ss += v[f] * v[f];
      ss += __shfl_xor(ss, 1);
      ss += __shfl_xor(ss, 2);
      ss += __shfl_xor(ss, 4);
      ss += __shfl_xor(ss, 8);
      float sc = 1.0f / fmaxf(sqrtf(ss), 1e-12f);
      if (gr < n) {
        unsigned short* out = (unsigned short*)outv;
#pragma unroll
        for (int f = 0; f < 8; ++f) {
          float o = fmaxf(v[f] * sc, 0.f);
          out[(size_t)gr * D + f * 16 + ln] = f2bf(o);
        }
      }
    } else {
      if (gr < n) {
        float* out = (float*)outv;
#pragma unroll
        for (int f = 0; f < 8; ++f) out[(size_t)gr * D + f * 16 + ln] = v[f];
      }
    }
  }
}

// ---------------- fused: dual GEMM (layer L, MODE 0) + projection (layer L+1) --------
// x1 tile routed through LDS (W2 region, dead after dual MFMA); global x1 also written.
__global__ __launch_bounds__(512, 4) void k_dual_proj(const unsigned short* __restrict__ A1,
                                                      const unsigned short* __restrict__ W1,
                                                      const float* __restrict__ bias,
                                                      const unsigned short* __restrict__ A2,
                                                      const unsigned short* __restrict__ W2,
                                                      unsigned short* __restrict__ x1out,
                                                      const unsigned short* __restrict__ Wp,
                                                      const float* __restrict__ biasP,
                                                      unsigned short* __restrict__ hout,
                                                      int n) {
  __shared__ __align__(16) unsigned short Wlds[2 * 128 * 128];
  int t = threadIdx.x;
  int wv = t >> 6, l = t & 63, lg = l >> 4, ln = l & 15;
  int rb = blockIdx.x * 128 + wv * 16;
  int arow = rb + ln;
  if (arow >= n) arow = n - 1;
  const s8v* A1p = (const s8v*)(A1 + (size_t)arow * D + lg * 8);
  const s8v* A2p = (const s8v*)(A2 + (size_t)arow * D + lg * 8);
  s8v a1[4], a2[4];
#pragma unroll
  for (int ks = 0; ks < 4; ++ks) { a1[ks] = A1p[ks * 4]; a2[ks] = A2p[ks * 4]; }

#pragma unroll
  for (int i = 0; i < 8; ++i) {
    int idx = t + i * 512;          // chunk 0..4095
    int mat = idx >> 11;
    int rem = idx & 2047;
    int r = rem >> 4, k = rem & 15;
    int c = k ^ (r & 7);
    const unsigned short* src = (mat ? W2 : W1) + r * 128 + c * 8;
    gload_lds16(src, &Wlds[idx * 8]);
  }
  __syncthreads();

  f32x4 acc[8];
#pragma unroll
  for (int f = 0; f < 8; ++f) acc[f] = (f32x4){0.f, 0.f, 0.f, 0.f};
#pragma unroll
  for (int ks = 0; ks < 4; ++ks) {
#pragma unroll
    for (int f = 0; f < 8; ++f) {
      int ch = swz_chunk(f * 16 + ln, ks * 4 + lg) * 8;
      s8v b1 = *(const s8v*)&Wlds[ch];
      s8v b2 = *(const s8v*)&Wlds[16384 + ch];
      acc[f] = __builtin_amdgcn_mfma_f32_16x16x32_bf16(a1[ks], b1, acc[f], 0, 0, 0);
      acc[f] = __builtin_amdgcn_mfma_f32_16x16x32_bf16(a2[ks], b2, acc[f], 0, 0, 0);
    }
  }
  __syncthreads();   // all waves done reading both W LDS regions

  // re-stage Wp over W1's region; hides under epilogue VALU
#pragma unroll
  for (int i = 0; i < 4; ++i) {
    int idx = t + i * 512;
    int r = idx >> 4, k = idx & 15;
    int c = k ^ (r & 7);
    gload_lds16(Wp + r * 128 + c * 8, &Wlds[idx * 8]);
  }

  // dual epilogue: norm + relu -> x1 (global bf16 + swizzled LDS tile in W2 region)
#pragma unroll
  for (int r = 0; r < 4; ++r) {
    int gr = rb + 4 * lg + r;
    int lrow = wv * 16 + 4 * lg + r;      // block-local row
    float v[8];
#pragma unroll
    for (int f = 0; f < 8; ++f) v[f] = acc[f][r] + bias[f * 16 + ln];
    float ss = 0.f;
#pragma unroll
    for (int f = 0; f < 8; ++f) ss += v[f] * v[f];
    ss += __shfl_xor(ss, 1);
    ss += __shfl_xor(ss, 2);
    ss += __shfl_xor(ss, 4);
    ss += __shfl_xor(ss, 8);
    float sc = 1.0f / fmaxf(sqrtf(ss), 1e-12f);
#pragma unroll
    for (int f = 0; f < 8; ++f) {
      float o = fmaxf(v[f] * sc, 0.f);
      unsigned short ob = f2bf(o);
      int col = f * 16 + ln;
      Wlds[16384 + swz_chunk(lrow, col >> 3) * 8 + (col & 7)] = ob;
      if (gr < n) x1out[(size_t)gr * D + col] = ob;
    }
  }

  __syncthreads();   // drains Wp gload_lds + x1 ds_writes

  // projection: A = x1 from LDS (W2 region), W = Wp in LDS (W1 region)
  int lrow2 = wv * 16 + ln;
  s8v ap[4];
#pragma unroll
  for (int ks = 0; ks < 4; ++ks)
    ap[ks] = *(const s8v*)&Wlds[16384 + swz_chunk(lrow2, ks * 4 + lg) * 8];

  f32x4 acc2[8];
#pragma unroll
  for (int f = 0; f < 8; ++f) acc2[f] = (f32x4){0.f, 0.f, 0.f, 0.f};
#pragma unroll
  for (int ks = 0; ks < 4; ++ks) {
#pragma unroll
    for (int f = 0; f < 8; ++f) {
      s8v b = *(const s8v*)&Wlds[swz_chunk(f * 16 + ln, ks * 4 + lg) * 8];
      acc2[f] = __builtin_amdgcn_mfma_f32_16x16x32_bf16(ap[ks], b, acc2[f], 0, 0, 0);
    }
  }

#pragma unroll
  for (int r = 0; r < 4; ++r) {
    int gr = rb + 4 * lg + r;
    if (gr < n) {
#pragma unroll
      for (int f = 0; f < 8; ++f) {
        int c = f * 16 + ln;
        float v = acc2[f][r] + biasP[c];
        v = fmaxf(v, 0.f);
        hout[(size_t)gr * D + c] = f2bf(v);
      }
    }
  }
}

extern "C" void kernel_launch(void* const* d_in, const int* in_sizes, int n_in,
                              void* d_out, int out_size, void* d_ws, size_t ws_size,
                              hipStream_t stream) {
  const float* x   = (const float*)d_in[0];
  const int*   ei  = (const int*)d_in[1];
  const float* Wp  = (const float*)d_in[2];
  const float* bp  = (const float*)d_in[3];
  const float* Wl  = (const float*)d_in[4];
  const float* bl  = (const float*)d_in[5];
  const float* Wr  = (const float*)d_in[6];
  const float* Wlo = (const float*)d_in[7];
  const float* blo = (const float*)d_in[8];
  const float* Wro = (const float*)d_in[9];

  const int N = in_sizes[0] / D;  // 100000
  const int E = in_sizes[1] / 2;  // 1600000
  const int* srcIdx = ei;
  const int* dstIdx = ei + E;

  const size_t ND = (size_t)N * D;

  unsigned short* xb   = (unsigned short*)d_ws;   // N*D bf16
  unsigned short* h    = xb + ND;
  unsigned short* aggB = h + ND;                  // aliased: padded pairs (u32) in CSR build
  unsigned short* x2   = aggB + ND;
  unsigned short* Wb   = x2 + ND;                 // 8*16384 bf16
  int* row_start  = (int*)(Wb + 8 * 16384);       // N
  int* degA       = row_start + N;                // N
  int* cursor     = degA + N;                     // 512 (bucket fill counts)
  int* csrCursor  = cursor + 512;                 // 1
  int* csr        = csrCursor + 1;                // E

  unsigned* pairs = (unsigned*)aggB;              // padded: KB * BCAP u32 (~8 MB)

  unsigned short* Wpb1 = Wb + 16384;
  unsigned short* Wlb0 = Wb + 2 * 16384;
  unsigned short* Wlb1 = Wb + 3 * 16384;
  unsigned short* Wrb0 = Wb + 4 * 16384;
  unsigned short* Wrb1 = Wb + 5 * 16384;
  unsigned short* Wlob = Wb + 6 * 16384;
  unsigned short* Wrob = Wb + 7 * 16384;

  unsigned short* x1 = (unsigned short*)d_out;  // scratch until final GEMM

  int gG  = (N + 127) / 128;           // 512-thr GEMM blocks (128 rows each)
  int gAg = (N * 16 + 255) / 256;      // aggregate: 16 threads per node
  int KB  = (N + 255) / 256;           // buckets (dst>>8)
  int gA  = (E + 8191) / 8192;         // partA blocks (512 thr x 8192 edges)
  int nC  = 56;                        // cvt blocks: 28672 float4 units / 512

  // ---- zero bucket cursors + csr cursor (513 contiguous ints) ----
  hipMemsetAsync(cursor, 0, 513 * sizeof(int), stream);

  // ---- dispatch A': partA || weight cvt || layer-0 projection (all independent) ----
  k_build_proj<<<gA + nC + gG, 512, 0, stream>>>(srcIdx, dstIdx, cursor, pairs, E,
                                                 Wp, Wl, Wr, Wlo, Wro, Wb,
                                                 x, bp, h, xb, N, gA, nC);

  // ---- partB: csr finalize ----
  k_partB<<<KB, 1024, 0, stream>>>(pairs, cursor, csrCursor, row_start, degA, csr, N);

  // ---- layer 0: aggregate, then fused dual + layer-1 projection ----
  k_aggregate<<<gAg, 256, 0, stream>>>(h, aggB, row_start, degA, csr, N);
  k_dual_proj<<<gG, 512, 0, stream>>>(aggB, Wlb0, bl, xb, Wrb0, x1,
                                      Wpb1, bp + D, h, N);

  // ---- layer 1 ----
  k_aggregate<<<gAg, 256, 0, stream>>>(h, aggB, row_start, degA, csr, N);
  k_gemm_dual<0><<<gG, 512, 0, stream>>>(aggB, Wlb1, bl + D, x1, Wrb1, (void*)x2, N);

  // ---- final layer ----
  k_aggregate<<<gAg, 256, 0, stream>>>(x2, aggB, row_start, degA, csr, N);
  k_gemm_dual<1><<<gG, 512, 0, stream>>>(aggB, Wlob, blo, x2, Wrob, d_out, N);
}

// Round 19
// 299.941 us; speedup vs baseline: 1.2755x; 1.2755x over previous
//
#include <hip/hip_runtime.h>
#include <math.h>

#define D 128
#define BCAP 5120   // padded pair-slots per bucket (mean 4096, sigma 64 -> +16 sigma)

typedef short s8v __attribute__((ext_vector_type(8)));
typedef float f32x4 __attribute__((ext_vector_type(4)));
typedef unsigned short u16x8 __attribute__((ext_vector_type(8)));

__device__ __forceinline__ unsigned short f2bf(float f) {
  union { float f; unsigned u; } c; c.f = f;
  unsigned u = c.u;
  unsigned r = (u + 0x7fffu + ((u >> 16) & 1u)) >> 16;
  return (unsigned short)r;
}

__device__ __forceinline__ void gload_lds16(const void* g, void* l) {
  __builtin_amdgcn_global_load_lds((const __attribute__((address_space(1))) void*)g,
                                   (__attribute__((address_space(3))) void*)l, 16, 0, 0);
}

// LDS fragment address: logical (row r, chunk c) stored at chunk (r*16 + (c ^ (r&7)))
__device__ __forceinline__ int swz_chunk(int r, int c) { return (r << 4) + (c ^ (r & 7)); }

// ---------------- dispatch A': partA || weight-cvt || proj layer-0 (3-way merge) -----
__global__ __launch_bounds__(512, 4) void k_build_proj(const int* __restrict__ src,
                                                       const int* __restrict__ dst,
                                                       int* __restrict__ cursor,
                                                       unsigned* __restrict__ pairs, int E_,
                                                       const float* __restrict__ Wp,
                                                       const float* __restrict__ Wl,
                                                       const float* __restrict__ Wr,
                                                       const float* __restrict__ Wlo,
                                                       const float* __restrict__ Wro,
                                                       unsigned short* __restrict__ Wb,
                                                       const float* __restrict__ Av,
                                                       const float* __restrict__ bias,
                                                       unsigned short* __restrict__ hout,
                                                       unsigned short* __restrict__ xb_out,
                                                       int n, int nA, int nC) {
  __shared__ __align__(16) unsigned short Wlds[128 * 128];
  __shared__ int hist[512];
  __shared__ int gbase[512];
  __shared__ int lim[512];
  int t = threadIdx.x;
  int bid = blockIdx.x;

  if (bid < nA) {
    // ---------------- partA ----------------
    int base = bid * 8192;
    hist[t] = 0;
    __syncthreads();
    unsigned p_[16];
    int k_[16];
#pragma unroll
    for (int i = 0; i < 16; i++) {
      int e = base + i * 512 + t;
      if (e < E_) {
        int s = src[e], d = dst[e];
        p_[i] = ((unsigned)s << 8) | (unsigned)(d & 255);
        k_[i] = d >> 8;
        atomicAdd(&hist[k_[i]], 1);
      } else {
        k_[i] = -1;
      }
    }
    __syncthreads();
    {
      int c = hist[t];
      int start = c ? atomicAdd(&cursor[t], c) : 0;
      gbase[t] = t * BCAP + start;
      lim[t] = BCAP - start;   // remaining capacity in this bucket
      hist[t] = 0;
    }
    __syncthreads();
#pragma unroll
    for (int i = 0; i < 16; i++) {
      if (k_[i] >= 0) {
        int r = atomicAdd(&hist[k_[i]], 1);
        if (r < lim[k_[i]]) pairs[gbase[k_[i]] + r] = p_[i];
      }
    }
  } else if (bid < nA + nC) {
    // ---------------- weight cvt: float4 units [4096, 32768) (skip Wp layer0) ------
    int i = 4096 + (bid - nA) * 512 + t;
    const float* s;
    int off;
    if (i < 8192)       { s = Wp;  off = 0; }
    else if (i < 16384) { s = Wl;  off = 8192; }
    else if (i < 24576) { s = Wr;  off = 16384; }
    else if (i < 28672) { s = Wlo; off = 24576; }
    else                { s = Wro; off = 28672; }
    float4 a = ((const float4*)s)[i - off];
    ushort4 o;
    o.x = f2bf(a.x); o.y = f2bf(a.y); o.z = f2bf(a.z); o.w = f2bf(a.w);
    ((ushort4*)Wb)[i] = o;
  } else {
    // ---------------- proj layer 0 (self-staged fp32 Wp) ----------------
    int pbid = bid - nA - nC;
    int wv = t >> 6, l = t & 63, lg = l >> 4, ln = l & 15;
    int rb = pbid * 128 + wv * 16;
    int arow = rb + ln;
    if (arow >= n) arow = n - 1;

    // stage Wp layer-0: fp32 -> bf16, swizzled chunks, register path
#pragma unroll
    for (int i = 0; i < 4; ++i) {
      int idx = t + i * 512;        // chunk 0..2047
      int r = idx >> 4, k = idx & 15;
      int c = k ^ (r & 7);
      const float* wsrc = Wp + r * 128 + c * 8;
      float4 f0 = *(const float4*)wsrc;
      float4 f1 = *(const float4*)(wsrc + 4);
      u16x8 wb;
      wb[0] = f2bf(f0.x); wb[1] = f2bf(f0.y); wb[2] = f2bf(f0.z); wb[3] = f2bf(f0.w);
      wb[4] = f2bf(f1.x); wb[5] = f2bf(f1.y); wb[6] = f2bf(f1.z); wb[7] = f2bf(f1.w);
      *(u16x8*)&Wlds[idx * 8] = wb;
    }

    s8v a[4];
    const float* Af = Av + (size_t)arow * D + lg * 8;
#pragma unroll
    for (int ks = 0; ks < 4; ++ks) {
      float4 f0 = *(const float4*)(Af + ks * 32);
      float4 f1 = *(const float4*)(Af + ks * 32 + 4);
      s8v av;
      av[0] = (short)f2bf(f0.x); av[1] = (short)f2bf(f0.y);
      av[2] = (short)f2bf(f0.z); av[3] = (short)f2bf(f0.w);
      av[4] = (short)f2bf(f1.x); av[5] = (short)f2bf(f1.y);
      av[6] = (short)f2bf(f1.z); av[7] = (short)f2bf(f1.w);
      a[ks] = av;
      *(s8v*)(xb_out + (size_t)arow * D + lg * 8 + ks * 32) = av;
    }
    __syncthreads();

    f32x4 acc[8];
#pragma unroll
    for (int f = 0; f < 8; ++f) acc[f] = (f32x4){0.f, 0.f, 0.f, 0.f};
#pragma unroll
    for (int ks = 0; ks < 4; ++ks) {
#pragma unroll
      for (int f = 0; f < 8; ++f) {
        s8v b = *(const s8v*)&Wlds[swz_chunk(f * 16 + ln, ks * 4 + lg) * 8];
        acc[f] = __builtin_amdgcn_mfma_f32_16x16x32_bf16(a[ks], b, acc[f], 0, 0, 0);
      }
    }

#pragma unroll
    for (int r = 0; r < 4; ++r) {
      int gr = rb + 4 * lg + r;
      if (gr < n) {
#pragma unroll
        for (int f = 0; f < 8; ++f) {
          int c = f * 16 + ln;
          float v = acc[f][r] + bias[c];
          v = fmaxf(v, 0.f);
          hout[(size_t)gr * D + c] = f2bf(v);
        }
      }
    }
  }
}

// ---------------- partB (standalone): one bucket/block, 1024 thr ----------------
__global__ __launch_bounds__(1024) void k_partB(const unsigned* __restrict__ pairs,
                                                const int* __restrict__ bcnt,
                                                int* __restrict__ csrCursor,
                                                int* __restrict__ row_start,
                                                int* __restrict__ deg,
                                                int* __restrict__ csr, int n) {
  __shared__ int cnt[256];
  __shared__ int scn[256];
  __shared__ int baseSh;
  int k = blockIdx.x, t = threadIdx.x;
  int node0 = k << 8;
  int len = bcnt[k];
  if (len > BCAP) len = BCAP;
  const unsigned* pb = pairs + (size_t)k * BCAP;
  if (t == 0) baseSh = atomicAdd(csrCursor, len);
  if (t < 256) cnt[t] = 0;
  __syncthreads();
  for (int p = t; p < len; p += 1024) atomicAdd(&cnt[pb[p] & 255], 1);
  __syncthreads();
  int c = 0;
  if (t < 256) { c = cnt[t]; scn[t] = c; }
  __syncthreads();
  for (int off = 1; off < 256; off <<= 1) {
    int xv = 0;
    if (t < 256 && t >= off) xv = scn[t - off];
    __syncthreads();
    if (t < 256) scn[t] += xv;
    __syncthreads();
  }
  if (t < 256) {
    int ex = scn[t] - c;
    int node = node0 + t;
    if (node < n) { row_start[node] = baseSh + ex; deg[node] = c; }
    cnt[t] = baseSh + ex;   // running cursor per node
  }
  __syncthreads();
  for (int p = t; p < len; p += 1024) {
    unsigned pr = pb[p];
    int slot = atomicAdd(&cnt[pr & 255], 1);
    csr[slot] = (int)(pr >> 8);
  }
}

// ---------------- mean aggregation: one node per 16-lane group ----------------
__global__ __launch_bounds__(256) void k_aggregate(const unsigned short* __restrict__ h,
                                                   unsigned short* __restrict__ agg,
                                                   const int* __restrict__ row_start,
                                                   const int* __restrict__ deg,
                                                   const int* __restrict__ csr, int n) {
  int node = (blockIdx.x * 256 + threadIdx.x) >> 4;
  int li = threadIdx.x & 15;
  if (node >= n) return;
  int rs0 = row_start[node];
  int dc = deg[node];
  const int* ce = csr + rs0;
  const char* base = (const char*)h + li * 16;   // row r chunk at base + r*256

  float accL[4], accH[4];
#pragma unroll
  for (int q = 0; q < 4; q++) { accL[q] = 0.f; accH[q] = 0.f; }

#define ACCR(v)                                                        \
  {                                                                    \
    unsigned dw[4] = {(v).x, (v).y, (v).z, (v).w};                     \
    _Pragma("unroll") for (int q = 0; q < 4; q++) {                    \
      accL[q] += __uint_as_float(dw[q] << 16);                         \
      accH[q] += __uint_as_float(dw[q] & 0xffff0000u);                 \
    }                                                                  \
  }

  int e = 0;
  bool more = (3 < dc);
  int s0 = 0, s1 = 0, s2 = 0, s3 = 0;
  if (more) { s0 = ce[0]; s1 = ce[1]; s2 = ce[2]; s3 = ce[3]; }
  while (more) {
    uint4 v0 = *(const uint4*)(base + (size_t)s0 * 256);
    uint4 v1 = *(const uint4*)(base + (size_t)s1 * 256);
    uint4 v2 = *(const uint4*)(base + (size_t)s2 * 256);
    uint4 v3 = *(const uint4*)(base + (size_t)s3 * 256);
    e += 4;
    more = (e + 3 < dc);
    if (more) { s0 = ce[e]; s1 = ce[e + 1]; s2 = ce[e + 2]; s3 = ce[e + 3]; }
    ACCR(v0); ACCR(v1); ACCR(v2); ACCR(v3);
  }
  if (e < dc)     { uint4 v = *(const uint4*)(base + (size_t)ce[e] * 256);     ACCR(v); }
  if (e + 1 < dc) { uint4 v = *(const uint4*)(base + (size_t)ce[e + 1] * 256); ACCR(v); }
  if (e + 2 < dc) { uint4 v = *(const uint4*)(base + (size_t)ce[e + 2] * 256); ACCR(v); }
#undef ACCR

  float iv = 1.0f / (float)(dc > 0 ? dc : 1);
  u16x8 o;
#pragma unroll
  for (int q = 0; q < 4; q++) {
    o[2 * q] = f2bf(accL[q] * iv);
    o[2 * q + 1] = f2bf(accH[q] * iv);
  }
  *(u16x8*)(agg + (size_t)node * D + li * 8) = o;
}

// ---------------- dual GEMM (async LDS-staged W1+W2): A1@W1^T + b + A2@W2^T ----------
// MODE 0: L2-normalize rows then relu, store bf16. MODE 1: store fp32.
template <int MODE>
__global__ __launch_bounds__(512, 4) void k_gemm_dual(const unsigned short* __restrict__ A1,
                                                      const unsigned short* __restrict__ W1,
                                                      const float* __restrict__ bias,
                                                      const unsigned short* __restrict__ A2,
                                                      const unsigned short* __restrict__ W2,
                                                      void* __restrict__ outv, int n) {
  __shared__ __align__(16) unsigned short Wlds[2 * 128 * 128];
  int t = threadIdx.x;
  int wv = t >> 6, l = t & 63, lg = l >> 4, ln = l & 15;
  int rb = blockIdx.x * 128 + wv * 16;
  int arow = rb + ln;
  if (arow >= n) arow = n - 1;
  const s8v* A1p = (const s8v*)(A1 + (size_t)arow * D + lg * 8);
  const s8v* A2p = (const s8v*)(A2 + (size_t)arow * D + lg * 8);
  s8v a1[4], a2[4];
#pragma unroll
  for (int ks = 0; ks < 4; ++ks) { a1[ks] = A1p[ks * 4]; a2[ks] = A2p[ks * 4]; }

#pragma unroll
  for (int i = 0; i < 8; ++i) {
    int idx = t + i * 512;          // chunk 0..4095
    int mat = idx >> 11;
    int rem = idx & 2047;
    int r = rem >> 4, k = rem & 15;
    int c = k ^ (r & 7);
    const unsigned short* src = (mat ? W2 : W1) + r * 128 + c * 8;
    gload_lds16(src, &Wlds[idx * 8]);
  }
  __syncthreads();

  f32x4 acc[8];
#pragma unroll
  for (int f = 0; f < 8; ++f) acc[f] = (f32x4){0.f, 0.f, 0.f, 0.f};

#pragma unroll
  for (int ks = 0; ks < 4; ++ks) {
#pragma unroll
    for (int f = 0; f < 8; ++f) {
      int ch = swz_chunk(f * 16 + ln, ks * 4 + lg) * 8;
      s8v b1 = *(const s8v*)&Wlds[ch];
      s8v b2 = *(const s8v*)&Wlds[16384 + ch];
      acc[f] = __builtin_amdgcn_mfma_f32_16x16x32_bf16(a1[ks], b1, acc[f], 0, 0, 0);
      acc[f] = __builtin_amdgcn_mfma_f32_16x16x32_bf16(a2[ks], b2, acc[f], 0, 0, 0);
    }
  }

#pragma unroll
  for (int r = 0; r < 4; ++r) {
    int gr = rb + 4 * lg + r;
    float v[8];
#pragma unroll
    for (int f = 0; f < 8; ++f) v[f] = acc[f][r] + bias[f * 16 + ln];
    if (MODE == 0) {
      float ss = 0.f;
#pragma unroll
      for (int f = 0; f < 8; ++f) ss += v[f] * v[f];
      ss += __shfl_xor(ss, 1);
      ss += __shfl_xor(ss, 2);
      ss += __shfl_xor(ss, 4);
      ss += __shfl_xor(ss, 8);
      float sc = 1.0f / fmaxf(sqrtf(ss), 1e-12f);
      if (gr < n) {
        unsigned short* out = (unsigned short*)outv;
#pragma unroll
        for (int f = 0; f < 8; ++f) {
          float o = fmaxf(v[f] * sc, 0.f);
          out[(size_t)gr * D + f * 16 + ln] = f2bf(o);
        }
      }
    } else {
      if (gr < n) {
        float* out = (float*)outv;
#pragma unroll
        for (int f = 0; f < 8; ++f) out[(size_t)gr * D + f * 16 + ln] = v[f];
      }
    }
  }
}

// ---------------- fused: dual GEMM (layer L, MODE 0) + projection (layer L+1) --------
// x1 tile routed through LDS (W2 region, dead after dual MFMA); global x1 also written.
__global__ __launch_bounds__(512, 4) void k_dual_proj(const unsigned short* __restrict__ A1,
                                                      const unsigned short* __restrict__ W1,
                                                      const float* __restrict__ bias,
                                                      const unsigned short* __restrict__ A2,
                                                      const unsigned short* __restrict__ W2,
                                                      unsigned short* __restrict__ x1out,
                                                      const unsigned short* __restrict__ Wp,
                                                      const float* __restrict__ biasP,
                                                      unsigned short* __restrict__ hout,
                                                      int n) {
  __shared__ __align__(16) unsigned short Wlds[2 * 128 * 128];
  int t = threadIdx.x;
  int wv = t >> 6, l = t & 63, lg = l >> 4, ln = l & 15;
  int rb = blockIdx.x * 128 + wv * 16;
  int arow = rb + ln;
  if (arow >= n) arow = n - 1;
  const s8v* A1p = (const s8v*)(A1 + (size_t)arow * D + lg * 8);
  const s8v* A2p = (const s8v*)(A2 + (size_t)arow * D + lg * 8);
  s8v a1[4], a2[4];
#pragma unroll
  for (int ks = 0; ks < 4; ++ks) { a1[ks] = A1p[ks * 4]; a2[ks] = A2p[ks * 4]; }

#pragma unroll
  for (int i = 0; i < 8; ++i) {
    int idx = t + i * 512;          // chunk 0..4095
    int mat = idx >> 11;
    int rem = idx & 2047;
    int r = rem >> 4, k = rem & 15;
    int c = k ^ (r & 7);
    const unsigned short* src = (mat ? W2 : W1) + r * 128 + c * 8;
    gload_lds16(src, &Wlds[idx * 8]);
  }
  __syncthreads();

  f32x4 acc[8];
#pragma unroll
  for (int f = 0; f < 8; ++f) acc[f] = (f32x4){0.f, 0.f, 0.f, 0.f};
#pragma unroll
  for (int ks = 0; ks < 4; ++ks) {
#pragma unroll
    for (int f = 0; f < 8; ++f) {
      int ch = swz_chunk(f * 16 + ln, ks * 4 + lg) * 8;
      s8v b1 = *(const s8v*)&Wlds[ch];
      s8v b2 = *(const s8v*)&Wlds[16384 + ch];
      acc[f] = __builtin_amdgcn_mfma_f32_16x16x32_bf16(a1[ks], b1, acc[f], 0, 0, 0);
      acc[f] = __builtin_amdgcn_mfma_f32_16x16x32_bf16(a2[ks], b2, acc[f], 0, 0, 0);
    }
  }
  __syncthreads();   // all waves done reading both W LDS regions

  // re-stage Wp over W1's region; hides under epilogue VALU
#pragma unroll
  for (int i = 0; i < 4; ++i) {
    int idx = t + i * 512;
    int r = idx >> 4, k = idx & 15;
    int c = k ^ (r & 7);
    gload_lds16(Wp + r * 128 + c * 8, &Wlds[idx * 8]);
  }

  // dual epilogue: norm + relu -> x1 (global bf16 + swizzled LDS tile in W2 region)
#pragma unroll
  for (int r = 0; r < 4; ++r) {
    int gr = rb + 4 * lg + r;
    int lrow = wv * 16 + 4 * lg + r;      // block-local row
    float v[8];
#pragma unroll
    for (int f = 0; f < 8; ++f) v[f] = acc[f][r] + bias[f * 16 + ln];
    float ss = 0.f;
#pragma unroll
    for (int f = 0; f < 8; ++f) ss += v[f] * v[f];
    ss += __shfl_xor(ss, 1);
    ss += __shfl_xor(ss, 2);
    ss += __shfl_xor(ss, 4);
    ss += __shfl_xor(ss, 8);
    float sc = 1.0f / fmaxf(sqrtf(ss), 1e-12f);
#pragma unroll
    for (int f = 0; f < 8; ++f) {
      float o = fmaxf(v[f] * sc, 0.f);
      unsigned short ob = f2bf(o);
      int col = f * 16 + ln;
      Wlds[16384 + swz_chunk(lrow, col >> 3) * 8 + (col & 7)] = ob;
      if (gr < n) x1out[(size_t)gr * D + col] = ob;
    }
  }

  __syncthreads();   // drains Wp gload_lds + x1 ds_writes

  // projection: A = x1 from LDS (W2 region), W = Wp in LDS (W1 region)
  int lrow2 = wv * 16 + ln;
  s8v ap[4];
#pragma unroll
  for (int ks = 0; ks < 4; ++ks)
    ap[ks] = *(const s8v*)&Wlds[16384 + swz_chunk(lrow2, ks * 4 + lg) * 8];

  f32x4 acc2[8];
#pragma unroll
  for (int f = 0; f < 8; ++f) acc2[f] = (f32x4){0.f, 0.f, 0.f, 0.f};
#pragma unroll
  for (int ks = 0; ks < 4; ++ks) {
#pragma unroll
    for (int f = 0; f < 8; ++f) {
      s8v b = *(const s8v*)&Wlds[swz_chunk(f * 16 + ln, ks * 4 + lg) * 8];
      acc2[f] = __builtin_amdgcn_mfma_f32_16x16x32_bf16(ap[ks], b, acc2[f], 0, 0, 0);
    }
  }

#pragma unroll
  for (int r = 0; r < 4; ++r) {
    int gr = rb + 4 * lg + r;
    if (gr < n) {
#pragma unroll
      for (int f = 0; f < 8; ++f) {
        int c = f * 16 + ln;
        float v = acc2[f][r] + biasP[c];
        v = fmaxf(v, 0.f);
        hout[(size_t)gr * D + c] = f2bf(v);
      }
    }
  }
}

extern "C" void kernel_launch(void* const* d_in, const int* in_sizes, int n_in,
                              void* d_out, int out_size, void* d_ws, size_t ws_size,
                              hipStream_t stream) {
  const float* x   = (const float*)d_in[0];
  const int*   ei  = (const int*)d_in[1];
  const float* Wp  = (const float*)d_in[2];
  const float* bp  = (const float*)d_in[3];
  const float* Wl  = (const float*)d_in[4];
  const float* bl  = (const float*)d_in[5];
  const float* Wr  = (const float*)d_in[6];
  const float* Wlo = (const float*)d_in[7];
  const float* blo = (const float*)d_in[8];
  const float* Wro = (const float*)d_in[9];

  const int N = in_sizes[0] / D;  // 100000
  const int E = in_sizes[1] / 2;  // 1600000
  const int* srcIdx = ei;
  const int* dstIdx = ei + E;

  const size_t ND = (size_t)N * D;

  unsigned short* xb   = (unsigned short*)d_ws;   // N*D bf16
  unsigned short* h    = xb + ND;
  unsigned short* aggB = h + ND;                  // aliased: padded pairs (u32) in CSR build
  unsigned short* x2   = aggB + ND;
  unsigned short* Wb   = x2 + ND;                 // 8*16384 bf16
  int* row_start  = (int*)(Wb + 8 * 16384);       // N
  int* degA       = row_start + N;                // N
  int* cursor     = degA + N;                     // 512 (bucket fill counts)
  int* csrCursor  = cursor + 512;                 // 1
  int* csr        = csrCursor + 1;                // E

  unsigned* pairs = (unsigned*)aggB;              // padded: KB * BCAP u32 (~8 MB)

  unsigned short* Wpb1 = Wb + 16384;
  unsigned short* Wlb0 = Wb + 2 * 16384;
  unsigned short* Wlb1 = Wb + 3 * 16384;
  unsigned short* Wrb0 = Wb + 4 * 16384;
  unsigned short* Wrb1 = Wb + 5 * 16384;
  unsigned short* Wlob = Wb + 6 * 16384;
  unsigned short* Wrob = Wb + 7 * 16384;

  unsigned short* x1 = (unsigned short*)d_out;  // scratch until final GEMM

  int gG  = (N + 127) / 128;           // 512-thr GEMM blocks (128 rows each)
  int gAg = (N * 16 + 255) / 256;      // aggregate: 16 threads per node
  int KB  = (N + 255) / 256;           // buckets (dst>>8)
  int gA  = (E + 8191) / 8192;         // partA blocks (512 thr x 8192 edges)
  int nC  = 56;                        // cvt blocks: 28672 float4 units / 512

  // ---- zero bucket cursors + csr cursor (513 contiguous ints) ----
  hipMemsetAsync(cursor, 0, 513 * sizeof(int), stream);

  // ---- dispatch A': partA || weight cvt || layer-0 projection (all independent) ----
  k_build_proj<<<gA + nC + gG, 512, 0, stream>>>(srcIdx, dstIdx, cursor, pairs, E,
                                                 Wp, Wl, Wr, Wlo, Wro, Wb,
                                                 x, bp, h, xb, N, gA, nC);

  // ---- partB: csr finalize ----
  k_partB<<<KB, 1024, 0, stream>>>(pairs, cursor, csrCursor, row_start, degA, csr, N);

  // ---- layer 0: aggregate, then fused dual + layer-1 projection ----
  k_aggregate<<<gAg, 256, 0, stream>>>(h, aggB, row_start, degA, csr, N);
  k_dual_proj<<<gG, 512, 0, stream>>>(aggB, Wlb0, bl, xb, Wrb0, x1,
                                      Wpb1, bp + D, h, N);

  // ---- layer 1 ----
  k_aggregate<<<gAg, 256, 0, stream>>>(h, aggB, row_start, degA, csr, N);
  k_gemm_dual<0><<<gG, 512, 0, stream>>>(aggB, Wlb1, bl + D, x1, Wrb1, (void*)x2, N);

  // ---- final layer ----
  k_aggregate<<<gAg, 256, 0, stream>>>(x2, aggB, row_start, degA, csr, N);
  k_gemm_dual<1><<<gG, 512, 0, stream>>>(aggB, Wlob, blo, x2, Wrob, d_out, N);
}